// Round 17
// baseline (1034.865 us; speedup 1.0000x reference)
//
#include <hip/hip_runtime.h>
#include <stdint.h>

#define DEV __device__ __forceinline__

using f32x4  = __attribute__((ext_vector_type(4))) float;
using bf16x8 = __attribute__((ext_vector_type(8))) short;
typedef unsigned short u16;
typedef unsigned int   u32;

typedef const __attribute__((address_space(1))) void* gptr_t;
typedef __attribute__((address_space(3))) void*       lptr_t;

DEV u16 f2bf(float f) {               // RTNE float -> bf16 bits
  union { float f; u32 u; } v; v.f = f;
  u32 lsb = (v.u >> 16) & 1u;
  v.u += 0x7fffu + lsb;
  return (u16)(v.u >> 16);
}
DEV float bf2f(u16 h) {
  union { u32 u; float f; } v; v.u = ((u32)h) << 16;
  return v.f;
}
DEV void async16(void* lds, const void* g) {
  __builtin_amdgcn_global_load_lds((gptr_t)(uintptr_t)g,
                                   (lptr_t)(u32)(uintptr_t)lds, 16, 0, 0);
}
// monotone float->uint key (ascending order preserved); bijective
DEV u32 fkey(float v) {
  u32 u = __float_as_uint(v);
  return u ^ ((u & 0x80000000u) ? 0xFFFFFFFFu : 0x80000000u);
}
DEV float unfkey(u32 key) {
  const u32 ub = (key & 0x80000000u) ? (key ^ 0x80000000u) : ~key;
  return __uint_as_float(ub);
}

// ---------------- fused split kernel: all four tensors, 4 elems/thread ----------------
__global__ __launch_bounds__(256) void splitall_kernel(
    const float* __restrict__ x,  const float* __restrict__ W1,
    const float* __restrict__ W2, const float* __restrict__ Wo,
    u16* __restrict__ x_hi, u16* __restrict__ x_lo,
    u16* __restrict__ W1h,  u16* __restrict__ W1l,
    u16* __restrict__ W2h,  u16* __restrict__ Woh,
    int nX4, int nW4, int nWo4)
{
  const int i4 = blockIdx.x * 256 + threadIdx.x;
  const int total4 = nX4 + 2 * nW4 + nWo4;
  if (i4 >= total4) return;
  if (i4 < nX4) {
    const int j = i4 * 4;
    const float4 v = *(const float4*)&x[j];
    const float vv[4] = { v.x, v.y, v.z, v.w };
    u16 h[4], l[4];
#pragma unroll
    for (int t = 0; t < 4; ++t) { h[t] = f2bf(vv[t]); l[t] = f2bf(vv[t] - bf2f(h[t])); }
    *(ushort4*)&x_hi[j] = make_ushort4(h[0], h[1], h[2], h[3]);
    *(ushort4*)&x_lo[j] = make_ushort4(l[0], l[1], l[2], l[3]);
  } else if (i4 < nX4 + nW4) {
    const int j = (i4 - nX4) * 4;
    const float4 v = *(const float4*)&W1[j];
    const float vv[4] = { v.x, v.y, v.z, v.w };
    u16 h[4], l[4];
#pragma unroll
    for (int t = 0; t < 4; ++t) { h[t] = f2bf(vv[t]); l[t] = f2bf(vv[t] - bf2f(h[t])); }
    *(ushort4*)&W1h[j] = make_ushort4(h[0], h[1], h[2], h[3]);
    *(ushort4*)&W1l[j] = make_ushort4(l[0], l[1], l[2], l[3]);
  } else if (i4 < nX4 + 2 * nW4) {
    const int j = (i4 - nX4 - nW4) * 4;
    const float4 v = *(const float4*)&W2[j];
    *(ushort4*)&W2h[j] = make_ushort4(f2bf(v.x), f2bf(v.y), f2bf(v.z), f2bf(v.w));
  } else {
    const int j = (i4 - nX4 - 2 * nW4) * 4;
    const float4 v = *(const float4*)&Wo[j];
    *(ushort4*)&Woh[j] = make_ushort4(f2bf(v.x), f2bf(v.y), f2bf(v.z), f2bf(v.w));
  }
}

// XCD-aware block swizzle (nwg % 8 == 0 for all our grids)
DEV void swz_block(int& bx, int& by) {
  const int gx = gridDim.x, nwg = gx * gridDim.y;
  const int lid = by * gx + bx;
  const int cpx = nwg >> 3;
  const int swz = (lid & 7) * cpx + (lid >> 3);
  bx = swz % gx; by = swz / gx;
}

// ======= fused z+gate: 8-phase 256x256 GEMM, role chosen per block =======
// [R13/R14/R16-verified engine & schedule — barriers/stages/vmcnt untouched;
// only segment-pointer/bound selection is runtime.]
// role z    (by < mrows): C = [xh|xh|xl].[W1h|W1l|W1h]^T, 3 segs, fp32 out
// role gate (by >= mrows): C = xh.W2h^T, 1 seg, bf16 out
// 512 threads = 8 waves (2M x 4N); LDS 128 KB; swizzle cs ^= (row&7) on global
// source + ds_read; stages p0/p1 -> buf1(t+1), p4/p5 -> buf0(t+2); vmcnt(0)
// gates at p3/p7 (loads issued 2-3 phases earlier -> latency hidden).
template<int K>
__global__ __launch_bounds__(512, 2) void gemmzg_kernel(
    const u16* __restrict__ xh, const u16* __restrict__ xl,
    const u16* __restrict__ W1h, const u16* __restrict__ W1l,
    const u16* __restrict__ W2h,
    float* __restrict__ zout, u16* __restrict__ gout,
    int N, int mrows)
{
  __shared__ u16 smem[65536];   // 128 KB

  const int tid  = threadIdx.x;
  const int lane = tid & 63;
  const int wid  = tid >> 6;
  const int wm = wid >> 2, wn = wid & 3;
  int bx = blockIdx.x, by = blockIdx.y;
  swz_block(bx, by);

  constexpr int TPS = K >> 6;               // tiles per segment
  const u16 *A0, *A1, *A2, *B0, *B1, *B2;
  int nTiles;
  bool isZ;
  if (by < mrows) {                          // z role
    isZ = true;
    A0 = xh; A1 = xh; A2 = xl;
    B0 = W1h; B1 = W1l; B2 = W1h;
    nTiles = 3 * TPS;
  } else {                                   // gate role
    isZ = false;
    by -= mrows;
    A0 = xh; A1 = xh; A2 = xh;
    B0 = W2h; B1 = W2h; B2 = W2h;
    nTiles = TPS;
  }
  const int m0 = by * 256, n0 = bx * 256;
  const int nIter = nTiles >> 1;

  f32x4 acc[8][4] = {};
  bf16x8 afr[4][2], bfr[2][2];

  auto stageHT = [&](int ab, int buf, int half, int ktile) {
    const int kt  = ktile < nTiles ? ktile : nTiles - 1;
    const int seg = kt / TPS;
    const int k0  = (kt - seg * TPS) << 6;
    const u16* __restrict__ src =
        ab ? (seg == 0 ? B0 : seg == 1 ? B1 : B2)
           : (seg == 0 ? A0 : seg == 1 ? A1 : A2);
    const int g0 = (ab ? n0 : m0) + half * 128;
    const int baseu = ((buf * 2 + ab) * 2 + half) * 8192;
#pragma unroll
    for (int L = 0; L < 2; ++L) {
      const int s = L * 512 + tid;
      const int r = s >> 3, cs = s & 7;
      const int csg = cs ^ (r & 7);
      async16(smem + baseu + (L * 512 + (tid & ~63)) * 8,
              src + (size_t)(g0 + r) * K + k0 + csg * 8);
    }
  };
  auto ldA = [&](int buf, int mi, int ks) -> bf16x8 {
    const int rA = wm * 128 + mi * 16 + (lane & 15);
    const int h = rA >> 7, rl = rA & 127;
    const int cs = (ks * 4 + (lane >> 4)) ^ (rl & 7);
    return *(const bf16x8*)&smem[((buf * 2 + 0) * 2 + h) * 8192 + rl * 64 + cs * 8];
  };
  auto ldB = [&](int buf, int ni, int ks) -> bf16x8 {
    const int rB = wn * 64 + ni * 16 + (lane & 15);
    const int h = rB >> 7, rl = rB & 127;
    const int cs = (ks * 4 + (lane >> 4)) ^ (rl & 7);
    return *(const bf16x8*)&smem[((buf * 2 + 1) * 2 + h) * 8192 + rl * 64 + cs * 8];
  };

  // prologue: tile0 -> buf0 (A h0/h1, B h0/h1), full drain, barrier
  stageHT(0, 0, 0, 0); stageHT(0, 0, 1, 0);
  stageHT(1, 0, 0, 0); stageHT(1, 0, 1, 0);
  asm volatile("s_waitcnt vmcnt(0)" ::: "memory");
  __builtin_amdgcn_sched_barrier(0);
  __builtin_amdgcn_s_barrier();
  __builtin_amdgcn_sched_barrier(0);

  for (int i = 0; i < nIter; ++i) {
    const int t2 = 2 * i;
#pragma unroll
    for (int p = 0; p < 8; ++p) {
      const int pm = p & 3, bufC = p >> 2;
      const int miB = (pm >> 1) * 4, niB = (pm & 1) * 2;
      if ((pm & 1) == 0) {
#pragma unroll
        for (int m = 0; m < 4; ++m)
#pragma unroll
          for (int ks = 0; ks < 2; ++ks)
            afr[m][ks] = ldA(bufC, miB + m, ks);
      }
#pragma unroll
      for (int n = 0; n < 2; ++n)
#pragma unroll
        for (int ks = 0; ks < 2; ++ks)
          bfr[n][ks] = ldB(bufC, niB + n, ks);
      // race-free staging (R13-verified table)
      if (p == 0)      { stageHT(0, 1, 0, t2 + 1); stageHT(0, 1, 1, t2 + 1); }
      else if (p == 1) { stageHT(1, 1, 0, t2 + 1); stageHT(1, 1, 1, t2 + 1); }
      else if (p == 4) { stageHT(0, 0, 0, t2 + 2); stageHT(0, 0, 1, t2 + 2); }
      else if (p == 5) { stageHT(1, 0, 0, t2 + 2); stageHT(1, 0, 1, t2 + 2); }
      __builtin_amdgcn_sched_barrier(0);
      __builtin_amdgcn_s_barrier();
      __builtin_amdgcn_sched_barrier(0);
      __builtin_amdgcn_s_setprio(1);
#pragma unroll
      for (int m = 0; m < 4; ++m)
#pragma unroll
        for (int n = 0; n < 2; ++n)
#pragma unroll
          for (int ks = 0; ks < 2; ++ks)
            acc[miB + m][niB + n] = __builtin_amdgcn_mfma_f32_16x16x32_bf16(
                afr[m][ks], bfr[n][ks], acc[miB + m][niB + n], 0, 0, 0);
      __builtin_amdgcn_s_setprio(0);
      if (pm == 3)
        asm volatile("s_waitcnt vmcnt(0)" ::: "memory");
      __builtin_amdgcn_sched_barrier(0);
      __builtin_amdgcn_s_barrier();
      __builtin_amdgcn_sched_barrier(0);
    }
  }
  asm volatile("s_waitcnt vmcnt(0)" ::: "memory");

  if (isZ) {
#pragma unroll
    for (int mi = 0; mi < 8; ++mi) {
      const int rb = m0 + wm * 128 + mi * 16 + (lane >> 4) * 4;
#pragma unroll
      for (int ni = 0; ni < 4; ++ni) {
        const int col = n0 + wn * 64 + ni * 16 + (lane & 15);
#pragma unroll
        for (int r2 = 0; r2 < 4; ++r2)
          zout[(size_t)(rb + r2) * N + col] = acc[mi][ni][r2];
      }
    }
  } else {
#pragma unroll
    for (int mi = 0; mi < 8; ++mi) {
      const int rb = m0 + wm * 128 + mi * 16 + (lane >> 4) * 4;
#pragma unroll
      for (int ni = 0; ni < 4; ++ni) {
        const int col = n0 + wn * 64 + ni * 16 + (lane & 15);
#pragma unroll
        for (int r2 = 0; r2 < 4; ++r2)
          gout[(size_t)(rb + r2) * N + col] = f2bf(acc[mi][ni][r2]);
      }
    }
  }
}

// ------- GEMM 1-pass bf16 128x128 (down-proj) — R8-validated, unchanged -------
template<int BK>
__global__ __launch_bounds__(256) void gemm_bt(
    const u16* __restrict__ A, const u16* __restrict__ B,
    float* __restrict__ C, int N, int K)
{
  constexpr int TILE = 128 * BK;
  __shared__ u16 smem[2 * TILE];
  u16* sA = smem;
  u16* sB = smem + TILE;

  const int tid  = threadIdx.x;
  const int lane = tid & 63;
  const int wave = tid >> 6;
  const int wr = wave >> 1, wc = wave & 1;
  int bx = blockIdx.x, by = blockIdx.y;
  swz_block(bx, by);
  const int m0 = by * 128, n0 = bx * 128;

  f32x4 acc[4][4] = {};
  constexpr int SPR   = BK / 8;
  constexpr int ITERS = (128 * SPR) / 256;

  for (int k0 = 0; k0 < K; k0 += BK) {
#pragma unroll
    for (int i = 0; i < ITERS; ++i) {
      const int slot = i * 256 + tid;
      const int r = slot / SPR, cc = slot % SPR;
      const int uni = (i * 256 + wave * 64) * 8;
      async16(sA + uni, A + (size_t)(m0 + r) * K + k0 + cc * 8);
      async16(sB + uni, B + (size_t)(n0 + r) * K + k0 + cc * 8);
    }
    __syncthreads();

#pragma unroll
    for (int ks = 0; ks < BK / 32; ++ks) {
      const int kb = ks * 32 + (lane >> 4) * 8;
      bf16x8 a[4], b[4];
#pragma unroll
      for (int i = 0; i < 4; ++i) {
        a[i] = *(const bf16x8*)&sA[(wr * 64 + i * 16 + (lane & 15)) * BK + kb];
        b[i] = *(const bf16x8*)&sB[(wc * 64 + i * 16 + (lane & 15)) * BK + kb];
      }
#pragma unroll
      for (int mi = 0; mi < 4; ++mi)
#pragma unroll
        for (int ni = 0; ni < 4; ++ni)
          acc[mi][ni] = __builtin_amdgcn_mfma_f32_16x16x32_bf16(a[mi], b[ni], acc[mi][ni], 0, 0, 0);
    }
    __syncthreads();
  }

#pragma unroll
  for (int mi = 0; mi < 4; ++mi) {
    const int rbase = m0 + wr * 64 + mi * 16 + (lane >> 4) * 4;
#pragma unroll
    for (int ni = 0; ni < 4; ++ni) {
      const int col = n0 + wc * 64 + ni * 16 + (lane & 15);
#pragma unroll
      for (int r2 = 0; r2 < 4; ++r2)
        C[(size_t)(rbase + r2) * N + col] = acc[mi][ni][r2];
    }
  }
}

// ---------------- per-row top-k select (3-pass z, narrow band, in-place g->s) -------
// [R14/R16-validated, unchanged] 22-step bisection on 3-pass z (hard err <= ~1.5e-4);
// band +/-8e-4 >= 2*eps + quantum with >2x margin; band re-ranked by bit-exact
// numpy-replica fp32 act keys (4-wide SSE lane chains, exact hadd combine),
// stable index tie-break. Writes s = act*gate in place over the gate buffer.
__global__ __launch_bounds__(256) void select9_kernel(
    const float* __restrict__ z, u16* __restrict__ gs,
    const float* __restrict__ xin, const float* __restrict__ W1,
    const int* __restrict__ kptr)
{
  const int row = blockIdx.x, tid = threadIdx.x;
  const int lane = tid & 63, wave = tid >> 6;
  const int k = *kptr;

  __shared__ float xrow[1024];
  __shared__ float sact[4096];
  __shared__ unsigned char flag[4096];
  __shared__ int wsum[4];
  __shared__ int s_nb;
  __shared__ int band_idx[256];
  __shared__ u32 band_key[256];
  __shared__ float band_act[256];

  const float* zrow = z + (size_t)row * 4096;
  u16* gsrow = gs + (size_t)row * 4096;

  float zreg[16];
#pragma unroll
  for (int q = 0; q < 4; ++q) {
    const float4 v = *(const float4*)&zrow[q * 1024 + tid * 4];
    zreg[q * 4 + 0] = v.x; zreg[q * 4 + 1] = v.y;
    zreg[q * 4 + 2] = v.z; zreg[q * 4 + 3] = v.w;
  }
  *(float4*)&xrow[tid * 4] = *(const float4*)&xin[(size_t)row * 1024 + tid * 4];
  *(u32*)&flag[tid * 4] = 0u;
  *(u32*)&flag[1024 + tid * 4] = 0u;
  *(u32*)&flag[2048 + tid * 4] = 0u;
  *(u32*)&flag[3072 + tid * 4] = 0u;
  if (tid == 0) s_nb = 0;
  __syncthreads();

  // 22-step MSB bisection for ~kth largest (register compares)
  u32 prefix = 0;
  for (int step = 0; step < 22; ++step) {
    const u32 c = prefix | (1u << (31 - step));
    const float zc = unfkey(c);
    int cnt = 0;
#pragma unroll
    for (int i = 0; i < 16; ++i) cnt += (zreg[i] >= zc) ? 1 : 0;
    for (int off = 32; off; off >>= 1) cnt += __shfl_xor(cnt, off);
    if (lane == 0) wsum[wave] = cnt;
    __syncthreads();
    const int tot = wsum[0] + wsum[1] + wsum[2] + wsum[3];
    if (tot >= k) prefix = c;
    __syncthreads();
  }
  const float tau = unfkey(prefix);
  const float BANDW = 8e-4f;
  const float thi = tau + BANDW, tlo = tau - BANDW;

  int cntD = 0;
#pragma unroll
  for (int q = 0; q < 4; ++q)
#pragma unroll
    for (int j = 0; j < 4; ++j) {
      const int f = q * 1024 + tid * 4 + j;
      const float zv = zreg[q * 4 + j];
      if (zv > thi) { flag[f] = 1; ++cntD; }
      else if (zv >= tlo) {
        const int p = atomicAdd(&s_nb, 1);
        if (p < 256) band_idx[p] = f;
      }
    }
  for (int off = 32; off; off >>= 1) cntD += __shfl_xor(cntD, off);
  if (lane == 0) wsum[wave] = cntD;
  __syncthreads();
  const int D = wsum[0] + wsum[1] + wsum[2] + wsum[3];
  const int nb = (s_nb < 256) ? s_nb : 256;
  const int need = k - D;

  // 4-wide numpy-replica dots (SSE lane chains, exact hadd combine)
  {
    const int gi = tid >> 2, l = tid & 3;
    const int wl = lane & ~3;
    for (int i = gi; i < nb; i += 64) {
      const int f = band_idx[i];
      const float* wr = W1 + (size_t)f * 1024;
      float v = 0.f;
#pragma unroll 8
      for (int b = 0; b < 1024; b += 16) {
        float t = __fadd_rn(__fmul_rn(xrow[b + 12 + l], wr[b + 12 + l]), v);
        t = __fadd_rn(__fmul_rn(xrow[b + 8 + l],  wr[b + 8 + l]),  t);
        t = __fadd_rn(__fmul_rn(xrow[b + 4 + l],  wr[b + 4 + l]),  t);
        v = __fadd_rn(__fmul_rn(xrow[b + 0 + l],  wr[b + 0 + l]),  t);
      }
      const float c0 = __shfl(v, wl + 0);
      const float c1 = __shfl(v, wl + 1);
      const float c2 = __shfl(v, wl + 2);
      const float c3 = __shfl(v, wl + 3);
      if (l == 0) {
        const float zrep = __fadd_rn(__fadd_rn(c0, c1), __fadd_rn(c2, c3));
        const double zd = (double)zrep;
        const float a = (float)(zd / (1.0 + exp(-zd)));
        band_act[i] = a;
        band_key[i] = fkey(a);
      }
    }
  }
  __syncthreads();

  // stable rank (exact key desc, index asc); selected band: flag=2, sact <- act
  for (int i = tid; i < nb; i += 256) {
    const u32 ki = band_key[i];
    const int fi = band_idx[i];
    int rank = 0;
    for (int j = 0; j < nb; ++j) {
      const u32 kj = band_key[j];
      rank += (kj > ki || (kj == ki && band_idx[j] < fi)) ? 1 : 0;
    }
    if (rank < need) { flag[fi] = 2; sact[fi] = band_act[i]; }
  }
  __syncthreads();

  // write s = act * gate (bf16, in place over gate)
#pragma unroll
  for (int q = 0; q < 4; ++q) {
    const int f0 = q * 1024 + tid * 4;
    const ushort4 gu = *(const ushort4*)&gsrow[f0];
    const float gvv[4] = { bf2f(gu.x), bf2f(gu.y), bf2f(gu.z), bf2f(gu.w) };
    const u32 fl = *(const u32*)&flag[f0];
    u16 out[4];
#pragma unroll
    for (int j = 0; j < 4; ++j) {
      const u32 fj = (fl >> (8 * j)) & 0xFF;
      float sval = 0.f;
      if (fj == 2) {
        sval = sact[f0 + j] * gvv[j];
      } else if (fj == 1) {
        const float zz = zreg[q * 4 + j];
        sval = (zz / (1.f + expf(-zz))) * gvv[j];
      }
      out[j] = f2bf(sval);
    }
    *(ushort4*)&gsrow[f0] = make_ushort4(out[0], out[1], out[2], out[3]);
  }
}

// ---------------- launch ----------------
extern "C" void kernel_launch(void* const* d_in, const int* in_sizes, int n_in,
                              void* d_out, int out_size, void* d_ws, size_t ws_size,
                              hipStream_t stream)
{
  const float* x  = (const float*)d_in[0];
  const float* W1 = (const float*)d_in[1];
  const float* W2 = (const float*)d_in[2];
  const float* Wo = (const float*)d_in[3];
  const int* kptr = (const int*)d_in[4];

  const int DM = 1024, DF = 4096;
  const int M = in_sizes[0] / DM;   // 8192 rows
  const size_t nX = (size_t)M * DM, nW = (size_t)DF * DM, nWo = (size_t)DM * DF;

  // fixed bf16 buffers: x hi/lo, W1 hi/lo, W2 hi, Wo hi
  char* w = (char*)d_ws;
  u16* x_hi  = (u16*)w;  w += nX * 2;
  u16* x_lo  = (u16*)w;  w += nX * 2;
  u16* W1_hi = (u16*)w;  w += nW * 2;
  u16* W1_lo = (u16*)w;  w += nW * 2;
  u16* W2_hi = (u16*)w;  w += nW * 2;
  u16* Wo_hi = (u16*)w;  w += nWo * 2;
  const size_t fixed_bytes = (size_t)(w - (char*)d_ws);

  // per-chunk: z fp32 (4) + g/s bf16 in-place (2) = 6 B/elem
  int nch = 1;
  while (nch < 64) {
    const size_t per = (size_t)(M / nch) * DF * 6;
    if (fixed_bytes + per <= ws_size) break;
    nch *= 2;
  }
  const int Mc = M / nch;

  float* zbuf  = (float*)w;
  u16*   gsbuf = (u16*)(w + (size_t)Mc * DF * 4);

  {
    const long long total4 = ((long long)nX + 2 * (long long)nW + (long long)nWo) / 4;
    splitall_kernel<<<dim3((int)((total4 + 255) / 256)), 256, 0, stream>>>(
        x, W1, W2, Wo, x_hi, x_lo, W1_hi, W1_lo, W2_hi, Wo_hi,
        (int)(nX / 4), (int)(nW / 4), (int)(nWo / 4));
  }

  for (int ch = 0; ch < nch; ++ch) {
    const size_t ro = (size_t)ch * Mc;
    // fused: z (3-seg split GEMM, fp32) + gate (1-seg, bf16) in one dispatch
    gemmzg_kernel<1024><<<dim3(DF / 256, 2 * (Mc / 256)), 512, 0, stream>>>(
        x_hi + ro * DM, x_lo + ro * DM, W1_hi, W1_lo, W2_hi,
        zbuf, gsbuf, DF, Mc / 256);
    // top-k: narrow band (8e-4) + replica keys; writes s in place over g
    select9_kernel<<<dim3(Mc), 256, 0, stream>>>(
        zbuf, gsbuf, x + ro * DM, W1, kptr);
    // out = s @ Wo^T (1-pass bf16, 128^2)
    gemm_bt<64><<<dim3(DM / 128, Mc / 128), 256, 0, stream>>>(
        gsbuf, Wo_hi, (float*)d_out + ro * DM, DM, DF);
  }
}

// Round 18
// 595.931 us; speedup vs baseline: 1.7366x; 1.7366x over previous
//
#include <hip/hip_runtime.h>
#include <stdint.h>

#define DEV __device__ __forceinline__

using f32x4  = __attribute__((ext_vector_type(4))) float;
using bf16x8 = __attribute__((ext_vector_type(8))) short;
typedef unsigned short u16;
typedef unsigned int   u32;

typedef const __attribute__((address_space(1))) void* gptr_t;
typedef __attribute__((address_space(3))) void*       lptr_t;

DEV u16 f2bf(float f) {               // RTNE float -> bf16 bits
  union { float f; u32 u; } v; v.f = f;
  u32 lsb = (v.u >> 16) & 1u;
  v.u += 0x7fffu + lsb;
  return (u16)(v.u >> 16);
}
DEV float bf2f(u16 h) {
  union { u32 u; float f; } v; v.u = ((u32)h) << 16;
  return v.f;
}
DEV void async16(void* lds, const void* g) {
  __builtin_amdgcn_global_load_lds((gptr_t)(uintptr_t)g,
                                   (lptr_t)(u32)(uintptr_t)lds, 16, 0, 0);
}
// monotone float->uint key (ascending order preserved); bijective
DEV u32 fkey(float v) {
  u32 u = __float_as_uint(v);
  return u ^ ((u & 0x80000000u) ? 0xFFFFFFFFu : 0x80000000u);
}
DEV float unfkey(u32 key) {
  const u32 ub = (key & 0x80000000u) ? (key ^ 0x80000000u) : ~key;
  return __uint_as_float(ub);
}

// ---------------- fused split kernel: all four tensors, 4 elems/thread ----------------
__global__ __launch_bounds__(256) void splitall_kernel(
    const float* __restrict__ x,  const float* __restrict__ W1,
    const float* __restrict__ W2, const float* __restrict__ Wo,
    u16* __restrict__ x_hi, u16* __restrict__ x_lo,
    u16* __restrict__ W1h,  u16* __restrict__ W1l,
    u16* __restrict__ W2h,  u16* __restrict__ Woh,
    int nX4, int nW4, int nWo4)
{
  const int i4 = blockIdx.x * 256 + threadIdx.x;
  const int total4 = nX4 + 2 * nW4 + nWo4;
  if (i4 >= total4) return;
  if (i4 < nX4) {
    const int j = i4 * 4;
    const float4 v = *(const float4*)&x[j];
    const float vv[4] = { v.x, v.y, v.z, v.w };
    u16 h[4], l[4];
#pragma unroll
    for (int t = 0; t < 4; ++t) { h[t] = f2bf(vv[t]); l[t] = f2bf(vv[t] - bf2f(h[t])); }
    *(ushort4*)&x_hi[j] = make_ushort4(h[0], h[1], h[2], h[3]);
    *(ushort4*)&x_lo[j] = make_ushort4(l[0], l[1], l[2], l[3]);
  } else if (i4 < nX4 + nW4) {
    const int j = (i4 - nX4) * 4;
    const float4 v = *(const float4*)&W1[j];
    const float vv[4] = { v.x, v.y, v.z, v.w };
    u16 h[4], l[4];
#pragma unroll
    for (int t = 0; t < 4; ++t) { h[t] = f2bf(vv[t]); l[t] = f2bf(vv[t] - bf2f(h[t])); }
    *(ushort4*)&W1h[j] = make_ushort4(h[0], h[1], h[2], h[3]);
    *(ushort4*)&W1l[j] = make_ushort4(l[0], l[1], l[2], l[3]);
  } else if (i4 < nX4 + 2 * nW4) {
    const int j = (i4 - nX4 - nW4) * 4;
    const float4 v = *(const float4*)&W2[j];
    *(ushort4*)&W2h[j] = make_ushort4(f2bf(v.x), f2bf(v.y), f2bf(v.z), f2bf(v.w));
  } else {
    const int j = (i4 - nX4 - 2 * nW4) * 4;
    const float4 v = *(const float4*)&Wo[j];
    *(ushort4*)&Woh[j] = make_ushort4(f2bf(v.x), f2bf(v.y), f2bf(v.z), f2bf(v.w));
  }
}

// XCD-aware block swizzle (nwg % 8 == 0 for all our grids)
DEV void swz_block(int& bx, int& by) {
  const int gx = gridDim.x, nwg = gx * gridDim.y;
  const int lid = by * gx + bx;
  const int cpx = nwg >> 3;
  const int swz = (lid & 7) * cpx + (lid >> 3);
  bx = swz % gx; by = swz / gx;
}

// ======= 8-phase 256x256 GEMM, segmented-K, 16x16x32 MFMA =======
// [R13/R14/R16-verified engine: 955-990 TF, 0 bank conflicts. ALL trip counts
// and segment selection are COMPILE-TIME (R17 lesson: runtime nTiles/role
// branching destroys the schedule codegen — template the role, never branch).]
// C = sum_seg Aseg * Bseg^T over NSEG K-segments of length K each.
//   z (NSEG=3): [xh|xh|xl] . [W1h|W1l|W1h]  — Markidis 3-pass, hard err <= ~1.5e-4
//   gate (NSEG=1): xh . W2h, OUTBF16 epilogue
// 512 threads = 8 waves (2M x 4N); LDS 128 KB; swizzle cs ^= (row&7) on global
// source + ds_read; stages p0/p1 -> buf1(t+1), p4/p5 -> buf0(t+2); vmcnt(0)
// gates at p3/p7 (loads issued 2-3 phases earlier -> latency hidden).
template<int K, int NSEG, bool OUTBF16>
__global__ __launch_bounds__(512, 2) void gemm8p_kernel(
    const u16* __restrict__ A0, const u16* __restrict__ A1, const u16* __restrict__ A2,
    const u16* __restrict__ B0, const u16* __restrict__ B1, const u16* __restrict__ B2,
    void* __restrict__ Cout, int N)
{
  __shared__ u16 smem[65536];   // 128 KB

  const int tid  = threadIdx.x;
  const int lane = tid & 63;
  const int wid  = tid >> 6;
  const int wm = wid >> 2, wn = wid & 3;
  int bx = blockIdx.x, by = blockIdx.y;
  swz_block(bx, by);
  const int m0 = by * 256, n0 = bx * 256;
  constexpr int TPS    = K >> 6;            // tiles per segment
  constexpr int nTiles = NSEG * TPS;
  constexpr int nIter  = nTiles / 2;

  f32x4 acc[8][4] = {};
  bf16x8 afr[4][2], bfr[2][2];

  auto stageHT = [&](int ab, int buf, int half, int ktile) {
    const int kt  = ktile < nTiles ? ktile : nTiles - 1;
    const int seg = kt / TPS;
    const int k0  = (kt - seg * TPS) << 6;
    const u16* __restrict__ src =
        ab ? (seg == 0 ? B0 : seg == 1 ? B1 : B2)
           : (seg == 0 ? A0 : seg == 1 ? A1 : A2);
    const int g0 = (ab ? n0 : m0) + half * 128;
    const int baseu = ((buf * 2 + ab) * 2 + half) * 8192;
#pragma unroll
    for (int L = 0; L < 2; ++L) {
      const int s = L * 512 + tid;
      const int r = s >> 3, cs = s & 7;
      const int csg = cs ^ (r & 7);
      async16(smem + baseu + (L * 512 + (tid & ~63)) * 8,
              src + (size_t)(g0 + r) * K + k0 + csg * 8);
    }
  };
  auto ldA = [&](int buf, int mi, int ks) -> bf16x8 {
    const int rA = wm * 128 + mi * 16 + (lane & 15);
    const int h = rA >> 7, rl = rA & 127;
    const int cs = (ks * 4 + (lane >> 4)) ^ (rl & 7);
    return *(const bf16x8*)&smem[((buf * 2 + 0) * 2 + h) * 8192 + rl * 64 + cs * 8];
  };
  auto ldB = [&](int buf, int ni, int ks) -> bf16x8 {
    const int rB = wn * 64 + ni * 16 + (lane & 15);
    const int h = rB >> 7, rl = rB & 127;
    const int cs = (ks * 4 + (lane >> 4)) ^ (rl & 7);
    return *(const bf16x8*)&smem[((buf * 2 + 1) * 2 + h) * 8192 + rl * 64 + cs * 8];
  };

  // prologue: tile0 -> buf0 (A h0/h1, B h0/h1), full drain, barrier
  stageHT(0, 0, 0, 0); stageHT(0, 0, 1, 0);
  stageHT(1, 0, 0, 0); stageHT(1, 0, 1, 0);
  asm volatile("s_waitcnt vmcnt(0)" ::: "memory");
  __builtin_amdgcn_sched_barrier(0);
  __builtin_amdgcn_s_barrier();
  __builtin_amdgcn_sched_barrier(0);

  for (int i = 0; i < nIter; ++i) {
    const int t2 = 2 * i;
#pragma unroll
    for (int p = 0; p < 8; ++p) {
      const int pm = p & 3, bufC = p >> 2;
      const int miB = (pm >> 1) * 4, niB = (pm & 1) * 2;
      if ((pm & 1) == 0) {
#pragma unroll
        for (int m = 0; m < 4; ++m)
#pragma unroll
          for (int ks = 0; ks < 2; ++ks)
            afr[m][ks] = ldA(bufC, miB + m, ks);
      }
#pragma unroll
      for (int n = 0; n < 2; ++n)
#pragma unroll
        for (int ks = 0; ks < 2; ++ks)
          bfr[n][ks] = ldB(bufC, niB + n, ks);
      // race-free staging (R13-verified table)
      if (p == 0)      { stageHT(0, 1, 0, t2 + 1); stageHT(0, 1, 1, t2 + 1); }
      else if (p == 1) { stageHT(1, 1, 0, t2 + 1); stageHT(1, 1, 1, t2 + 1); }
      else if (p == 4) { stageHT(0, 0, 0, t2 + 2); stageHT(0, 0, 1, t2 + 2); }
      else if (p == 5) { stageHT(1, 0, 0, t2 + 2); stageHT(1, 0, 1, t2 + 2); }
      __builtin_amdgcn_sched_barrier(0);
      __builtin_amdgcn_s_barrier();
      __builtin_amdgcn_sched_barrier(0);
      __builtin_amdgcn_s_setprio(1);
#pragma unroll
      for (int m = 0; m < 4; ++m)
#pragma unroll
        for (int n = 0; n < 2; ++n)
#pragma unroll
          for (int ks = 0; ks < 2; ++ks)
            acc[miB + m][niB + n] = __builtin_amdgcn_mfma_f32_16x16x32_bf16(
                afr[m][ks], bfr[n][ks], acc[miB + m][niB + n], 0, 0, 0);
      __builtin_amdgcn_s_setprio(0);
      if (pm == 3)
        asm volatile("s_waitcnt vmcnt(0)" ::: "memory");
      __builtin_amdgcn_sched_barrier(0);
      __builtin_amdgcn_s_barrier();
      __builtin_amdgcn_sched_barrier(0);
    }
  }
  asm volatile("s_waitcnt vmcnt(0)" ::: "memory");

#pragma unroll
  for (int mi = 0; mi < 8; ++mi) {
    const int rb = m0 + wm * 128 + mi * 16 + (lane >> 4) * 4;
#pragma unroll
    for (int ni = 0; ni < 4; ++ni) {
      const int col = n0 + wn * 64 + ni * 16 + (lane & 15);
#pragma unroll
      for (int r2 = 0; r2 < 4; ++r2) {
        if constexpr (OUTBF16)
          ((u16*)Cout)[(size_t)(rb + r2) * N + col] = f2bf(acc[mi][ni][r2]);
        else
          ((float*)Cout)[(size_t)(rb + r2) * N + col] = acc[mi][ni][r2];
      }
    }
  }
}

// ------- GEMM 1-pass bf16 128x128 (down-proj) — R8-validated; K now constexpr -------
template<int BK, int K>
__global__ __launch_bounds__(256) void gemm_bt(
    const u16* __restrict__ A, const u16* __restrict__ B,
    float* __restrict__ C, int N)
{
  constexpr int TILE = 128 * BK;
  __shared__ u16 smem[2 * TILE];
  u16* sA = smem;
  u16* sB = smem + TILE;

  const int tid  = threadIdx.x;
  const int lane = tid & 63;
  const int wave = tid >> 6;
  const int wr = wave >> 1, wc = wave & 1;
  int bx = blockIdx.x, by = blockIdx.y;
  swz_block(bx, by);
  const int m0 = by * 128, n0 = bx * 128;

  f32x4 acc[4][4] = {};
  constexpr int SPR   = BK / 8;
  constexpr int ITERS = (128 * SPR) / 256;

  for (int k0 = 0; k0 < K; k0 += BK) {
#pragma unroll
    for (int i = 0; i < ITERS; ++i) {
      const int slot = i * 256 + tid;
      const int r = slot / SPR, cc = slot % SPR;
      const int uni = (i * 256 + wave * 64) * 8;
      async16(sA + uni, A + (size_t)(m0 + r) * K + k0 + cc * 8);
      async16(sB + uni, B + (size_t)(n0 + r) * K + k0 + cc * 8);
    }
    __syncthreads();

#pragma unroll
    for (int ks = 0; ks < BK / 32; ++ks) {
      const int kb = ks * 32 + (lane >> 4) * 8;
      bf16x8 a[4], b[4];
#pragma unroll
      for (int i = 0; i < 4; ++i) {
        a[i] = *(const bf16x8*)&sA[(wr * 64 + i * 16 + (lane & 15)) * BK + kb];
        b[i] = *(const bf16x8*)&sB[(wc * 64 + i * 16 + (lane & 15)) * BK + kb];
      }
#pragma unroll
      for (int mi = 0; mi < 4; ++mi)
#pragma unroll
        for (int ni = 0; ni < 4; ++ni)
          acc[mi][ni] = __builtin_amdgcn_mfma_f32_16x16x32_bf16(a[mi], b[ni], acc[mi][ni], 0, 0, 0);
    }
    __syncthreads();
  }

#pragma unroll
  for (int mi = 0; mi < 4; ++mi) {
    const int rbase = m0 + wr * 64 + mi * 16 + (lane >> 4) * 4;
#pragma unroll
    for (int ni = 0; ni < 4; ++ni) {
      const int col = n0 + wc * 64 + ni * 16 + (lane & 15);
#pragma unroll
      for (int r2 = 0; r2 < 4; ++r2)
        C[(size_t)(rbase + r2) * N + col] = acc[mi][ni][r2];
    }
  }
}

// ---------------- per-row top-k select (3-pass z, narrow band, in-place g->s) -------
// [R14/R16-validated, unchanged] 22-step bisection on 3-pass z (hard err <= ~1.5e-4);
// band +/-8e-4 >= 2*eps + quantum with >2x margin; band re-ranked by bit-exact
// numpy-replica fp32 act keys (4-wide SSE lane chains, exact hadd combine),
// stable index tie-break. Writes s = act*gate in place over the gate buffer.
__global__ __launch_bounds__(256) void select9_kernel(
    const float* __restrict__ z, u16* __restrict__ gs,
    const float* __restrict__ xin, const float* __restrict__ W1,
    const int* __restrict__ kptr)
{
  const int row = blockIdx.x, tid = threadIdx.x;
  const int lane = tid & 63, wave = tid >> 6;
  const int k = *kptr;

  __shared__ float xrow[1024];
  __shared__ float sact[4096];
  __shared__ unsigned char flag[4096];
  __shared__ int wsum[4];
  __shared__ int s_nb;
  __shared__ int band_idx[256];
  __shared__ u32 band_key[256];
  __shared__ float band_act[256];

  const float* zrow = z + (size_t)row * 4096;
  u16* gsrow = gs + (size_t)row * 4096;

  float zreg[16];
#pragma unroll
  for (int q = 0; q < 4; ++q) {
    const float4 v = *(const float4*)&zrow[q * 1024 + tid * 4];
    zreg[q * 4 + 0] = v.x; zreg[q * 4 + 1] = v.y;
    zreg[q * 4 + 2] = v.z; zreg[q * 4 + 3] = v.w;
  }
  *(float4*)&xrow[tid * 4] = *(const float4*)&xin[(size_t)row * 1024 + tid * 4];
  *(u32*)&flag[tid * 4] = 0u;
  *(u32*)&flag[1024 + tid * 4] = 0u;
  *(u32*)&flag[2048 + tid * 4] = 0u;
  *(u32*)&flag[3072 + tid * 4] = 0u;
  if (tid == 0) s_nb = 0;
  __syncthreads();

  // 22-step MSB bisection for ~kth largest (register compares)
  u32 prefix = 0;
  for (int step = 0; step < 22; ++step) {
    const u32 c = prefix | (1u << (31 - step));
    const float zc = unfkey(c);
    int cnt = 0;
#pragma unroll
    for (int i = 0; i < 16; ++i) cnt += (zreg[i] >= zc) ? 1 : 0;
    for (int off = 32; off; off >>= 1) cnt += __shfl_xor(cnt, off);
    if (lane == 0) wsum[wave] = cnt;
    __syncthreads();
    const int tot = wsum[0] + wsum[1] + wsum[2] + wsum[3];
    if (tot >= k) prefix = c;
    __syncthreads();
  }
  const float tau = unfkey(prefix);
  const float BANDW = 8e-4f;
  const float thi = tau + BANDW, tlo = tau - BANDW;

  int cntD = 0;
#pragma unroll
  for (int q = 0; q < 4; ++q)
#pragma unroll
    for (int j = 0; j < 4; ++j) {
      const int f = q * 1024 + tid * 4 + j;
      const float zv = zreg[q * 4 + j];
      if (zv > thi) { flag[f] = 1; ++cntD; }
      else if (zv >= tlo) {
        const int p = atomicAdd(&s_nb, 1);
        if (p < 256) band_idx[p] = f;
      }
    }
  for (int off = 32; off; off >>= 1) cntD += __shfl_xor(cntD, off);
  if (lane == 0) wsum[wave] = cntD;
  __syncthreads();
  const int D = wsum[0] + wsum[1] + wsum[2] + wsum[3];
  const int nb = (s_nb < 256) ? s_nb : 256;
  const int need = k - D;

  // 4-wide numpy-replica dots (SSE lane chains, exact hadd combine)
  {
    const int gi = tid >> 2, l = tid & 3;
    const int wl = lane & ~3;
    for (int i = gi; i < nb; i += 64) {
      const int f = band_idx[i];
      const float* wr = W1 + (size_t)f * 1024;
      float v = 0.f;
#pragma unroll 8
      for (int b = 0; b < 1024; b += 16) {
        float t = __fadd_rn(__fmul_rn(xrow[b + 12 + l], wr[b + 12 + l]), v);
        t = __fadd_rn(__fmul_rn(xrow[b + 8 + l],  wr[b + 8 + l]),  t);
        t = __fadd_rn(__fmul_rn(xrow[b + 4 + l],  wr[b + 4 + l]),  t);
        v = __fadd_rn(__fmul_rn(xrow[b + 0 + l],  wr[b + 0 + l]),  t);
      }
      const float c0 = __shfl(v, wl + 0);
      const float c1 = __shfl(v, wl + 1);
      const float c2 = __shfl(v, wl + 2);
      const float c3 = __shfl(v, wl + 3);
      if (l == 0) {
        const float zrep = __fadd_rn(__fadd_rn(c0, c1), __fadd_rn(c2, c3));
        const double zd = (double)zrep;
        const float a = (float)(zd / (1.0 + exp(-zd)));
        band_act[i] = a;
        band_key[i] = fkey(a);
      }
    }
  }
  __syncthreads();

  // stable rank (exact key desc, index asc); selected band: flag=2, sact <- act
  for (int i = tid; i < nb; i += 256) {
    const u32 ki = band_key[i];
    const int fi = band_idx[i];
    int rank = 0;
    for (int j = 0; j < nb; ++j) {
      const u32 kj = band_key[j];
      rank += (kj > ki || (kj == ki && band_idx[j] < fi)) ? 1 : 0;
    }
    if (rank < need) { flag[fi] = 2; sact[fi] = band_act[i]; }
  }
  __syncthreads();

  // write s = act * gate (bf16, in place over gate)
#pragma unroll
  for (int q = 0; q < 4; ++q) {
    const int f0 = q * 1024 + tid * 4;
    const ushort4 gu = *(const ushort4*)&gsrow[f0];
    const float gvv[4] = { bf2f(gu.x), bf2f(gu.y), bf2f(gu.z), bf2f(gu.w) };
    const u32 fl = *(const u32*)&flag[f0];
    u16 out[4];
#pragma unroll
    for (int j = 0; j < 4; ++j) {
      const u32 fj = (fl >> (8 * j)) & 0xFF;
      float sval = 0.f;
      if (fj == 2) {
        sval = sact[f0 + j] * gvv[j];
      } else if (fj == 1) {
        const float zz = zreg[q * 4 + j];
        sval = (zz / (1.f + expf(-zz))) * gvv[j];
      }
      out[j] = f2bf(sval);
    }
    *(ushort4*)&gsrow[f0] = make_ushort4(out[0], out[1], out[2], out[3]);
  }
}

// ---------------- launch ----------------
extern "C" void kernel_launch(void* const* d_in, const int* in_sizes, int n_in,
                              void* d_out, int out_size, void* d_ws, size_t ws_size,
                              hipStream_t stream)
{
  const float* x  = (const float*)d_in[0];
  const float* W1 = (const float*)d_in[1];
  const float* W2 = (const float*)d_in[2];
  const float* Wo = (const float*)d_in[3];
  const int* kptr = (const int*)d_in[4];

  const int DM = 1024, DF = 4096;
  const int M = in_sizes[0] / DM;   // 8192 rows
  const size_t nX = (size_t)M * DM, nW = (size_t)DF * DM, nWo = (size_t)DM * DF;

  // fixed bf16 buffers: x hi/lo, W1 hi/lo, W2 hi, Wo hi
  char* w = (char*)d_ws;
  u16* x_hi  = (u16*)w;  w += nX * 2;
  u16* x_lo  = (u16*)w;  w += nX * 2;
  u16* W1_hi = (u16*)w;  w += nW * 2;
  u16* W1_lo = (u16*)w;  w += nW * 2;
  u16* W2_hi = (u16*)w;  w += nW * 2;
  u16* Wo_hi = (u16*)w;  w += nWo * 2;
  const size_t fixed_bytes = (size_t)(w - (char*)d_ws);

  // per-chunk: z fp32 (4) + g/s bf16 in-place (2) = 6 B/elem
  int nch = 1;
  while (nch < 64) {
    const size_t per = (size_t)(M / nch) * DF * 6;
    if (fixed_bytes + per <= ws_size) break;
    nch *= 2;
  }
  const int Mc = M / nch;

  float* zbuf  = (float*)w;
  u16*   gsbuf = (u16*)(w + (size_t)Mc * DF * 4);

  {
    const long long total4 = ((long long)nX + 2 * (long long)nW + (long long)nWo) / 4;
    splitall_kernel<<<dim3((int)((total4 + 255) / 256)), 256, 0, stream>>>(
        x, W1, W2, Wo, x_hi, x_lo, W1_hi, W1_lo, W2_hi, Wo_hi,
        (int)(nX / 4), (int)(nW / 4), (int)(nWo / 4));
  }

  for (int ch = 0; ch < nch; ++ch) {
    const size_t ro = (size_t)ch * Mc;
    // z = 3-pass split GEMM [xh|xh|xl].[W1h|W1l|W1h], K'=3072, fp32 out
    gemm8p_kernel<1024, 3, false><<<dim3(DF / 256, Mc / 256), 512, 0, stream>>>(
        x_hi + ro * DM, x_hi + ro * DM, x_lo + ro * DM,
        W1_hi, W1_lo, W1_hi, zbuf, DF);
    // gate = xh . W2h, 1-pass, bf16 out
    gemm8p_kernel<1024, 1, true><<<dim3(DF / 256, Mc / 256), 512, 0, stream>>>(
        x_hi + ro * DM, x_hi + ro * DM, x_hi + ro * DM,
        W2_hi, W2_hi, W2_hi, gsbuf, DF);
    // top-k: narrow band (8e-4) + replica keys; writes s in place over g
    select9_kernel<<<dim3(Mc), 256, 0, stream>>>(
        zbuf, gsbuf, x + ro * DM, W1, kptr);
    // out = s @ Wo^T (1-pass bf16, 128^2, constexpr K)
    gemm_bt<64, 4096><<<dim3(DM / 128, Mc / 128), 256, 0, stream>>>(
        gsbuf, Wo_hi, (float*)d_out + ro * DM, DM);
  }
}